// Round 6
// baseline (268.871 us; speedup 1.0000x reference)
//
#include <hip/hip_runtime.h>

// EdgeLoss: mean |sobel_mag(gray(pred)) - sobel_mag(gray(target))|
// pred/target: (32, 3, 512, 512) fp32, output: scalar fp32.
//
// R6/R7 post-mortem: reg double-buffer pipeline = 107us, occ 10.6%, 1.17
// TB/s, and L3-warm dispatches ran the SAME time -> per-wave ILP/MLP never
// materializes (effective <1 load in flight/wave). Across R2..R7, perf
// tracks occupancy only. Lever = TLP + continuous VMEM issue.
//
// R8: m13-copy-shaped streaming kernel. Grid-stride, no LDS, no barriers,
// no pipelining. Thread = one float4 output chunk (4 px); reloads its 3
// input rows (vertical reuse delegated to L2/L3 - inputs are 201MB, fully
// L3-resident: R6 cold dispatch fetched only 122MB). Per (row,img): 3
// coalesced float4 channel loads + 6 scalar halo loads (L1 hits), gray in
// regs, Sobel direct. Images sequential to keep VGPR low -> target 16+
// waves/CU. 2048 blocks x 4 uniform trips; 1 atomic/block.

#define BATCH 32
#define HH 512
#define WW 512
#define IMG ((size_t)HH * WW)
#define CHUNKS 128                    // float4 chunks per row
#define TOTAL (BATCH * HH * CHUNKS)   // 2097152 threads of work
#define GRID 2048                     // x256 thr -> 4 trips, no tail

__global__ void zero_out_kernel(float* out) { out[0] = 0.0f; }

__device__ __forceinline__ float gray1(float r, float g, float b) {
    return 0.299f * r + 0.587f * g + 0.114f * b;
}

// Sobel magnitude, same expression structure as R2..R7 (all passed):
// a = row y-1, b = row y, c = row y+1 ; 0=j-1, 1=j, 2=j+1
#define MAG(a0, a1, a2, b0, b2, c0, c1, c2)                              \
    ({ float ex_ = ((a2) - (a0)) + 2.0f * ((b2) - (b0)) + ((c2) - (c0)); \
       float ey_ = ((c0) - (a0)) + 2.0f * ((c1) - (a1)) + ((c2) - (a2)); \
       sqrtf(ex_ * ex_ + ey_ * ey_); })

// Edge magnitudes for 4 px (x0..x0+3) of row `row`, one image.
// g[k][i] = gray of row (row-1+k), col (x0-1+i), zero outside the image.
__device__ __forceinline__ void edges4(const float* __restrict__ base,
                                       int row, int x0, bool okl, bool okr,
                                       float e[4])
{
    float g[3][6];
    #pragma unroll
    for (int k = 0; k < 3; ++k) {
        const int gy = row - 1 + k;
        if ((unsigned)gy < (unsigned)HH) {
            const float* rbase = base + (size_t)gy * WW;
            const float4 mr = *(const float4*)(rbase + x0);
            const float4 mg = *(const float4*)(rbase + IMG + x0);
            const float4 mb = *(const float4*)(rbase + 2 * IMG + x0);
            float lr = 0.f, lg = 0.f, lb = 0.f;
            float rr = 0.f, rg = 0.f, rb = 0.f;
            if (okl) {
                lr = rbase[x0 - 1];
                lg = rbase[IMG + x0 - 1];
                lb = rbase[2 * IMG + x0 - 1];
            }
            if (okr) {
                rr = rbase[x0 + 4];
                rg = rbase[IMG + x0 + 4];
                rb = rbase[2 * IMG + x0 + 4];
            }
            g[k][0] = gray1(lr, lg, lb);       // 0 when !okl (border)
            g[k][1] = gray1(mr.x, mg.x, mb.x);
            g[k][2] = gray1(mr.y, mg.y, mb.y);
            g[k][3] = gray1(mr.z, mg.z, mb.z);
            g[k][4] = gray1(mr.w, mg.w, mb.w);
            g[k][5] = gray1(rr, rg, rb);       // 0 when !okr (border)
        } else {
            #pragma unroll
            for (int i = 0; i < 6; ++i) g[k][i] = 0.f;
        }
    }
    #pragma unroll
    for (int j = 0; j < 4; ++j)
        e[j] = MAG(g[0][j], g[0][j + 1], g[0][j + 2],
                   g[1][j],             g[1][j + 2],
                   g[2][j], g[2][j + 1], g[2][j + 2]);
}

__global__ __launch_bounds__(256, 4) void edge_loss_kernel(
    const float* __restrict__ pred,
    const float* __restrict__ target,
    float* __restrict__ out)
{
    const int tid = threadIdx.x;
    float lsum = 0.0f;

    for (int idx = blockIdx.x * 256 + tid; idx < TOTAL; idx += GRID * 256) {
        const int img   = idx >> 16;          // 512 rows * 128 chunks = 65536
        const int row   = (idx >> 7) & 511;
        const int chunk = idx & 127;
        const int x0    = chunk << 2;
        const bool okl  = (chunk > 0);
        const bool okr  = (chunk < CHUNKS - 1);

        const float* pb = pred   + (size_t)img * 3 * IMG;
        const float* tb = target + (size_t)img * 3 * IMG;

        float ep[4], et[4];
        edges4(pb, row, x0, okl, okr, ep);
        edges4(tb, row, x0, okl, okr, et);

        lsum += fabsf(ep[0] - et[0]) + fabsf(ep[1] - et[1])
              + fabsf(ep[2] - et[2]) + fabsf(ep[3] - et[3]);
    }

    // ---- reduce: wave shuffle -> cross-wave LDS -> one atomic per block ----
    #pragma unroll
    for (int off = 32; off > 0; off >>= 1)
        lsum += __shfl_down(lsum, off, 64);

    __shared__ float wsum[4];
    const int lane = tid & 63;
    const int wav  = tid >> 6;
    if (lane == 0) wsum[wav] = lsum;
    __syncthreads();
    if (tid == 0) {
        const float s = wsum[0] + wsum[1] + wsum[2] + wsum[3];
        const float inv_n = 1.0f / ((float)BATCH * HH * WW);
        atomicAdd(out, s * inv_n);
    }
}

extern "C" void kernel_launch(void* const* d_in, const int* in_sizes, int n_in,
                              void* d_out, int out_size, void* d_ws, size_t ws_size,
                              hipStream_t stream) {
    const float* pred   = (const float*)d_in[0];
    const float* target = (const float*)d_in[1];
    float* out = (float*)d_out;

    // d_out is poisoned 0xAA before every timed launch -> zero it on-stream.
    zero_out_kernel<<<1, 1, 0, stream>>>(out);

    edge_loss_kernel<<<dim3(GRID, 1, 1), 256, 0, stream>>>(pred, target, out);
}